// Round 3
// baseline (18.783 us; speedup 1.0000x reference)
//
#include <hip/hip_runtime.h>

#define BATCH 1024
#define READ  128
#define N_TOT 514   // reversed order: [d2/v2, d1/v1, slots 511..0]
#define PF    16    // rows prefetched unconditionally (w==0 beyond n_used)

__global__ __launch_bounds__(64) void nm_summary_kernel(
    const float* __restrict__ values,  // (512, 1024, 128)
    const float* __restrict__ S,       // (512, 1024, 1)
    const float* __restrict__ u,       // (1024, 1)
    const float* __restrict__ d1,      // (1024, 1)
    const float* __restrict__ d2,      // (1024, 1)
    const float* __restrict__ v1,      // (1024, 128)
    const float* __restrict__ v2,      // (1024, 128)
    float* __restrict__ out)           // (1024, 128)
{
    const int b    = blockIdx.x;
    const int lane = threadIdx.x;      // one wave per block; float2 per lane

    // ---- issue all loads up front; latencies overlap ----
    const float ub = u[b];
    float s = (lane == 0) ? d2[b]
            : (lane == 1) ? d1[b]
            : S[(size_t)(513 - lane) * BATCH + b];

    float2 pf[PF];
    pf[0] = ((const float2*)(v2 + (size_t)b * READ))[lane];
    pf[1] = ((const float2*)(v1 + (size_t)b * READ))[lane];
    #pragma unroll
    for (int n = 2; n < PF; ++n) {
        const float2* row =
            (const float2*)(values + ((size_t)(513 - n) * BATCH + b) * (size_t)READ);
        pf[n] = row[lane];
    }

    // ---- 64-wide inclusive scan; lane n ends up holding w[n] in-register ----
    float x = s;
    #pragma unroll
    for (int off = 1; off < 64; off <<= 1) {
        float t = __shfl_up(x, off, 64);
        if (lane >= off) x += t;
    }
    const float w     = fminf(s, fmaxf(ub - (x - s), 0.0f));
    const float carry = __shfl(x, 63, 64);                 // chunk-0 total (uniform)
    const unsigned long long m = __ballot(w > 0.0f);

    // ---- fast path: accumulate PF prefetched rows, weights via shuffle ----
    float2 acc = make_float2(0.0f, 0.0f);
    #pragma unroll
    for (int n = 0; n < PF; ++n) {
        const float wn = __shfl(w, n, 64);
        acc.x = fmaf(pf[n].x, wn, acc.x);
        acc.y = fmaf(pf[n].y, wn, acc.y);
    }

    // ---- rare tail: nonzero weights past PF, or scan must continue ----
    if ((m >> PF) != 0ull || carry < ub) {
        for (int n = PF; n < 64; ++n) {
            const float wn = __shfl(w, n, 64);             // uniform across wave
            if (wn > 0.0f) {
                const float2* row = (const float2*)
                    (values + ((size_t)(513 - n) * BATCH + b) * (size_t)READ);
                const float2 v = row[lane];
                acc.x = fmaf(v.x, wn, acc.x);
                acc.y = fmaf(v.y, wn, acc.y);
            }
        }
        float carry2 = carry;
        for (int c = 64; c < N_TOT && carry2 < ub; c += 64) {
            const int i = c + lane;
            float s2 = (i < N_TOT) ? S[(size_t)(513 - i) * BATCH + b] : 0.0f;
            float x2 = s2;
            #pragma unroll
            for (int off = 1; off < 64; off <<= 1) {
                float t = __shfl_up(x2, off, 64);
                if (lane >= off) x2 += t;
            }
            const float w2 = fminf(s2, fmaxf(ub - (carry2 + x2 - s2), 0.0f));
            for (int n = 0; n < 64; ++n) {
                const float wn = __shfl(w2, n, 64);
                if (wn > 0.0f) {
                    const float2* row = (const float2*)
                        (values + ((size_t)(513 - (c + n)) * BATCH + b) * (size_t)READ);
                    const float2 v = row[lane];
                    acc.x = fmaf(v.x, wn, acc.x);
                    acc.y = fmaf(v.y, wn, acc.y);
                }
            }
            carry2 += __shfl(x2, 63, 64);
        }
    }

    ((float2*)(out + (size_t)b * READ))[lane] = acc;
}

extern "C" void kernel_launch(void* const* d_in, const int* in_sizes, int n_in,
                              void* d_out, int out_size, void* d_ws, size_t ws_size,
                              hipStream_t stream) {
    const float* values = (const float*)d_in[0];
    const float* S      = (const float*)d_in[1];
    const float* u      = (const float*)d_in[2];
    const float* d1     = (const float*)d_in[3];
    const float* d2     = (const float*)d_in[4];
    const float* v1     = (const float*)d_in[5];
    const float* v2     = (const float*)d_in[6];
    float* out = (float*)d_out;

    nm_summary_kernel<<<dim3(BATCH), dim3(64), 0, stream>>>(
        values, S, u, d1, d2, v1, v2, out);
}

// Round 4
// 9.735 us; speedup vs baseline: 1.9294x; 1.9294x over previous
//
#include <hip/hip_runtime.h>

#define N_SLOTS 512
#define BATCH   1024
#define READ    128
#define N_TOT   514     // reversed order: [d2/v2, d1/v1, slots 511..0]
#define PF      16      // rows prefetched unconditionally (w==0 beyond n_used)

__global__ __launch_bounds__(64) void nm_summary_kernel(
    const float* __restrict__ values,  // (512, 1024, 128)
    const float* __restrict__ S,       // (512, 1024, 1)
    const float* __restrict__ u,       // (1024, 1)
    const float* __restrict__ d1,      // (1024, 1)
    const float* __restrict__ d2,      // (1024, 1)
    const float* __restrict__ v1,      // (1024, 128)
    const float* __restrict__ v2,      // (1024, 128)
    float* __restrict__ out)           // (1024, 128)
{
    const int b    = blockIdx.x;
    const int lane = threadIdx.x;      // one wave; each lane owns 2 r's via float2

    __shared__ float w_lds[N_TOT];

    // ---- issue the scan's inputs first (so their waitcnt doesn't drain pf) ----
    const float ub = u[b];
    // first-chunk strengths: rev idx 0->d2, 1->d1, i>=2 -> S[513-i]
    float s = (lane == 0) ? d2[b]
            : (lane == 1) ? d1[b]
            : S[(size_t)(513 - lane) * BATCH + b];

    // ---- issue PF row prefetches; latency overlaps the scan below ----
    float2 pf[PF];
    pf[0] = ((const float2*)(v2 + (size_t)b * READ))[lane];
    pf[1] = ((const float2*)(v1 + (size_t)b * READ))[lane];
    #pragma unroll
    for (int n = 2; n < PF; ++n) {
        const float2* row =
            (const float2*)(values + ((size_t)(513 - n) * BATCH + b) * (size_t)READ);
        pf[n] = row[lane];
    }

    // ---- 64-wide inclusive scan, chunk 0 (covers u<=4 in virtually all cases) ----
    float carry = 0.0f;
    int   n_used = 0;
    {
        float x = s;
        #pragma unroll
        for (int off = 1; off < 64; off <<= 1) {
            float t = __shfl_up(x, off, 64);
            if (lane >= off) x += t;
        }
        const float cum_prev = x - s;
        const float w = fminf(s, fmaxf(ub - cum_prev, 0.0f));
        w_lds[lane] = w;
        const unsigned long long m = __ballot(w > 0.0f);
        if (m) n_used = (63 - __builtin_clzll(m)) + 1;
        carry = __shfl(x, 63, 64);
    }
    // rare continuation: sum of first 64 strengths < u
    for (int c = 64; c < N_TOT && carry < ub; c += 64) {
        const int i = c + lane;
        float s2 = (i < N_TOT) ? S[(size_t)(513 - i) * BATCH + b] : 0.0f;
        float x = s2;
        #pragma unroll
        for (int off = 1; off < 64; off <<= 1) {
            float t = __shfl_up(x, off, 64);
            if (lane >= off) x += t;
        }
        const float cum_prev = carry + x - s2;
        const float w = fminf(s2, fmaxf(ub - cum_prev, 0.0f));
        if (i < N_TOT) w_lds[i] = w;
        const unsigned long long m = __ballot(w > 0.0f);
        if (m) n_used = c + (63 - __builtin_clzll(m)) + 1;
        carry += __shfl(x, 63, 64);
    }
    __syncthreads();   // single wave: compiles to waitcnt (+ cheap barrier)

    // ---- accumulate: prefetched rows (w==0 past n_used makes this exact) ----
    float2 acc = make_float2(0.0f, 0.0f);
    #pragma unroll
    for (int n = 0; n < PF; ++n) {
        const float w = w_lds[n];
        acc.x = fmaf(pf[n].x, w, acc.x);
        acc.y = fmaf(pf[n].y, w, acc.y);
    }
    // rare tail beyond the prefetch window
    for (int n = PF; n < n_used; ++n) {
        const float w = w_lds[n];
        const float2* row =
            (const float2*)(values + ((size_t)(513 - n) * BATCH + b) * (size_t)READ);
        const float2 v = row[lane];
        acc.x = fmaf(v.x, w, acc.x);
        acc.y = fmaf(v.y, w, acc.y);
    }

    ((float2*)(out + (size_t)b * READ))[lane] = acc;
}

extern "C" void kernel_launch(void* const* d_in, const int* in_sizes, int n_in,
                              void* d_out, int out_size, void* d_ws, size_t ws_size,
                              hipStream_t stream) {
    const float* values = (const float*)d_in[0];
    const float* S      = (const float*)d_in[1];
    const float* u      = (const float*)d_in[2];
    const float* d1     = (const float*)d_in[3];
    const float* d2     = (const float*)d_in[4];
    const float* v1     = (const float*)d_in[5];
    const float* v2     = (const float*)d_in[6];
    float* out = (float*)d_out;

    nm_summary_kernel<<<dim3(BATCH), dim3(64), 0, stream>>>(
        values, S, u, d1, d2, v1, v2, out);
}